// Round 1
// baseline (4206.917 us; speedup 1.0000x reference)
//
#include <hip/hip_runtime.h>
#include <math.h>

#define NN 50000
#define TT 4
#define FF 128
#define EE 800000

// ---------------- utility ----------------
__global__ void k_zero_f(float* __restrict__ p, int n){
  int i = blockIdx.x*256 + threadIdx.x;
  if(i<n) p[i]=0.f;
}
__global__ void k_zero2i(int* __restrict__ a, int* __restrict__ b, int n){
  int i = blockIdx.x*256 + threadIdx.x;
  if(i<n){ a[i]=0; b[i]=0; }
}
__global__ void k_copy(const float* __restrict__ a, float* __restrict__ b, int n){
  int i = blockIdx.x*256 + threadIdx.x;
  if(i<n) b[i]=a[i];
}

// count out-degree (src) for norm and in-degree (dst) for CSR
__global__ void k_count(const int* __restrict__ src, const int* __restrict__ dst,
                        int* __restrict__ deg, int* __restrict__ cnt){
  int i = blockIdx.x*256 + threadIdx.x;
  if(i<EE){ atomicAdd(&deg[src[i]],1); atomicAdd(&cnt[dst[i]],1); }
}

// single-workgroup scan: offsets (exclusive), dinv, cursor zeroing
__global__ __launch_bounds__(1024) void k_scan(const int* __restrict__ cnt, const int* __restrict__ deg,
                       int* __restrict__ offs, float* __restrict__ dinv, int* __restrict__ cur){
  __shared__ int sd[1024];
  int tid = threadIdx.x;
  int run = 0;
  for(int base=0;base<NN;base+=1024){
    int i = base+tid;
    int c = (i<NN)?cnt[i]:0;
    sd[tid]=c; __syncthreads();
    for(int off=1;off<1024;off<<=1){
      int v = (tid>=off)? sd[tid-off]:0;
      __syncthreads();
      sd[tid]+=v;
      __syncthreads();
    }
    int incl = sd[tid];
    if(i<NN){
      offs[i] = run + incl - c;
      int d = deg[i];
      dinv[i] = d>0 ? rsqrtf((float)d) : 0.f;
      cur[i]=0;
    }
    run += sd[1023];
    __syncthreads();
  }
  if(tid==0) offs[NN] = run;
}

// build dst-sorted CSR of (src, w) pairs
__global__ void k_scatter(const int* __restrict__ src, const int* __restrict__ dst,
                          const float* __restrict__ dinv, const int* __restrict__ offs,
                          int* __restrict__ cur, int* __restrict__ srcs, float* __restrict__ wsrt){
  int i = blockIdx.x*256 + threadIdx.x;
  if(i<EE){
    int s=src[i], d=dst[i];
    float w = -dinv[s]*dinv[d];
    int pos = offs[d] + atomicAdd(&cur[d],1);
    srcs[pos]=s; wsrt[pos]=w;
  }
}

// gather-SpMM: out[row,:] = sum_e w[e] * X[src[e],:]  (one wave per row, float2/lane)
// if X0 != null: out = 2*acc - X0[row,:]   (Chebyshev recurrence)
__global__ void k_spmm(const int* __restrict__ offs, const int* __restrict__ srcs,
                       const float* __restrict__ wsrt, const float* __restrict__ X,
                       const float* __restrict__ X0, float* __restrict__ out){
  int wid = threadIdx.x>>6, lane = threadIdx.x&63;
  int row = blockIdx.x*4+wid;
  if(row>=NN) return;
  int beg = offs[row], end = offs[row+1];
  const float2* X2 = (const float2*)X;
  float ax=0.f, ay=0.f;
  int e = beg;
  for(; e+3<end; e+=4){
    int s0=srcs[e+0], s1=srcs[e+1], s2=srcs[e+2], s3=srcs[e+3];
    float w0=wsrt[e+0], w1=wsrt[e+1], w2=wsrt[e+2], w3=wsrt[e+3];
    float2 v0=X2[s0*64+lane], v1=X2[s1*64+lane], v2=X2[s2*64+lane], v3=X2[s3*64+lane];
    ax = fmaf(w0,v0.x,ax); ay = fmaf(w0,v0.y,ay);
    ax = fmaf(w1,v1.x,ax); ay = fmaf(w1,v1.y,ay);
    ax = fmaf(w2,v2.x,ax); ay = fmaf(w2,v2.y,ay);
    ax = fmaf(w3,v3.x,ax); ay = fmaf(w3,v3.y,ay);
  }
  for(; e<end; ++e){
    int s=srcs[e]; float w=wsrt[e];
    float2 v=X2[s*64+lane];
    ax = fmaf(w,v.x,ax); ay = fmaf(w,v.y,ay);
  }
  int oi = row*64+lane;
  if(X0){
    float2 x0 = ((const float2*)X0)[oi];
    ax = 2.f*ax - x0.x; ay = 2.f*ay - x0.y;
  }
  float2 r; r.x=ax; r.y=ay;
  ((float2*)out)[oi]=r;
}

// C[r, coloff + c] (+)= sum_k A_chunk(k)[r,:] @ B[k,:]   A split in 128-col chunks
// B is K x Fo row-major. Optional bias+relu epilogue.
__global__ __launch_bounds__(256) void k_gemm(
    const float* __restrict__ A0, const float* __restrict__ A1, const float* __restrict__ A2,
    const float* __restrict__ B, float* __restrict__ C,
    int K, int Fo, int ldc, int coloff, int beta,
    const float* __restrict__ bias, int act){
  __shared__ float As[64][17];
  __shared__ float Bs[16][64];
  int tid = threadIdx.x;
  int tx = tid & 15, ty = tid >> 4;
  int bm = blockIdx.x, bn = blockIdx.y;
  float acc[4][4] = {{0.f}};
  int lr = tid>>2, lkv = tid&3;
  int lkk = tid>>4, lcv = tid&15;
  int arow = bm*64 + lr; if(arow >= NN) arow = NN-1;
  int nkb = K>>4;
  for(int kb=0; kb<nkb; ++kb){
    int koff = kb<<4;
    const float* Ac = (koff<128)?A0:((koff<256)?A1:A2);
    int kloc = koff & 127;
    float4 av = *(const float4*)(Ac + arow*128 + kloc + lkv*4);
    float4 bv = *(const float4*)(B + (koff+lkk)*Fo + bn*64 + lcv*4);
    As[lr][lkv*4+0]=av.x; As[lr][lkv*4+1]=av.y; As[lr][lkv*4+2]=av.z; As[lr][lkv*4+3]=av.w;
    *(float4*)(&Bs[lkk][lcv*4]) = bv;
    __syncthreads();
    #pragma unroll
    for(int kk=0;kk<16;++kk){
      float a0=As[ty*4+0][kk], a1=As[ty*4+1][kk], a2=As[ty*4+2][kk], a3=As[ty*4+3][kk];
      float4 b = *(const float4*)(&Bs[kk][tx*4]);
      acc[0][0]=fmaf(a0,b.x,acc[0][0]); acc[0][1]=fmaf(a0,b.y,acc[0][1]);
      acc[0][2]=fmaf(a0,b.z,acc[0][2]); acc[0][3]=fmaf(a0,b.w,acc[0][3]);
      acc[1][0]=fmaf(a1,b.x,acc[1][0]); acc[1][1]=fmaf(a1,b.y,acc[1][1]);
      acc[1][2]=fmaf(a1,b.z,acc[1][2]); acc[1][3]=fmaf(a1,b.w,acc[1][3]);
      acc[2][0]=fmaf(a2,b.x,acc[2][0]); acc[2][1]=fmaf(a2,b.y,acc[2][1]);
      acc[2][2]=fmaf(a2,b.z,acc[2][2]); acc[2][3]=fmaf(a2,b.w,acc[2][3]);
      acc[3][0]=fmaf(a3,b.x,acc[3][0]); acc[3][1]=fmaf(a3,b.y,acc[3][1]);
      acc[3][2]=fmaf(a3,b.z,acc[3][2]); acc[3][3]=fmaf(a3,b.w,acc[3][3]);
    }
    __syncthreads();
  }
  int row0 = bm*64 + ty*4;
  int col  = bn*64 + tx*4;
  #pragma unroll
  for(int i=0;i<4;++i){
    int r = row0+i;
    if(r<NN){
      float4 v; v.x=acc[i][0]; v.y=acc[i][1]; v.z=acc[i][2]; v.w=acc[i][3];
      if(bias){ v.x+=bias[col]; v.y+=bias[col+1]; v.z+=bias[col+2]; v.w+=bias[col+3]; }
      if(act){ v.x=fmaxf(v.x,0.f); v.y=fmaxf(v.y,0.f); v.z=fmaxf(v.z,0.f); v.w=fmaxf(v.w,0.f); }
      float* cp = C + r*ldc + coloff + col;
      if(beta){ float4 o=*(const float4*)cp; v.x+=o.x; v.y+=o.y; v.z+=o.z; v.w+=o.w; }
      *(float4*)cp = v;
    }
  }
}

// Z = sigmoid(OX[:,0:128]+bxz+bhz); HR = H * sigmoid(OX[:,128:256]+bxr+bhr)
__global__ void k_combA(const float* __restrict__ OX, const float* __restrict__ H,
                        const float* __restrict__ bxz, const float* __restrict__ bhz,
                        const float* __restrict__ bxr, const float* __restrict__ bhr,
                        float* __restrict__ Z, float* __restrict__ HR){
  int i = blockIdx.x*256 + threadIdx.x;
  if(i>=NN*FF) return;
  int r = i>>7, c = i&127;
  float zv = OX[r*384+c]     + bxz[c] + bhz[c];
  float rv = OX[r*384+128+c] + bxr[c] + bhr[c];
  zv = 1.f/(1.f+expf(-zv));
  rv = 1.f/(1.f+expf(-rv));
  Z[i]=zv; HR[i]=H[i]*rv;
}

// Htilde = tanh(OX[:,256:384]+bxh+bhh); Hnew = Z*H + (1-Z)*Htilde
__global__ void k_combB(const float* __restrict__ OX, const float* __restrict__ Z,
                        const float* __restrict__ H, const float* __restrict__ bxh,
                        const float* __restrict__ bhh, float* __restrict__ Hn){
  int i = blockIdx.x*256 + threadIdx.x;
  if(i>=NN*FF) return;
  int r = i>>7, c = i&127;
  float ht = tanhf(OX[r*384+256+c] + bxh[c] + bhh[c]);
  float z = Z[i];
  Hn[i] = z*H[i] + (1.f-z)*ht;
}

// pack column-concat weight blocks: B[(k*128+i), w*128+j] = Ww[k,i,j]
__global__ void k_pack(const float* __restrict__ W0, const float* __restrict__ W1,
                       const float* __restrict__ W2, float* __restrict__ B, int nw){
  int total = 384*nw*128;
  int i = blockIdx.x*256 + threadIdx.x;
  if(i>=total) return;
  int ncol = nw*128;
  int row = i/ncol, col = i - row*ncol;
  int wsel = col>>7, j = col&127;
  const float* W = (wsel==0)?W0:((wsel==1)?W1:W2);
  B[i] = W[row*128 + j];
}

extern "C" void kernel_launch(void* const* d_in, const int* in_sizes, int n_in,
                              void* d_out, int out_size, void* d_ws, size_t ws_size,
                              hipStream_t stream) {
  const float* x   = (const float*)d_in[0];
  const int*   ei  = (const int*)d_in[1];
  const float* Wxz = (const float*)d_in[2];
  const float* Whz = (const float*)d_in[3];
  const float* Wxr = (const float*)d_in[4];
  const float* Whr = (const float*)d_in[5];
  const float* Wxh = (const float*)d_in[6];
  const float* Whh = (const float*)d_in[7];
  const float* bxz = (const float*)d_in[8];
  const float* bhz = (const float*)d_in[9];
  const float* bxr = (const float*)d_in[10];
  const float* bhr = (const float*)d_in[11];
  const float* bxh = (const float*)d_in[12];
  const float* bhh = (const float*)d_in[13];
  const float* Wd1 = (const float*)d_in[14];
  const float* bd1 = (const float*)d_in[15];
  const float* Wd2 = (const float*)d_in[16];
  const float* bd2 = (const float*)d_in[17];
  float* out = (float*)d_out;

  char* p = (char*)d_ws;
  auto alloc = [&](size_t bytes)->void*{ void* r = (void*)p; p += (bytes+255)&~(size_t)255; return r; };
  const size_t NFB = (size_t)NN*FF*4;
  float* Ha   = (float*)alloc(NFB);
  float* Hb   = (float*)alloc(NFB);
  float* A1   = (float*)alloc(NFB);
  float* A2   = (float*)alloc(NFB);
  float* A3   = (float*)alloc(NFB);
  float* A4   = (float*)alloc(NFB);
  float* OX   = (float*)alloc((size_t)NN*384*4);
  float* Zb   = (float*)alloc(NFB);
  float* Bx   = (float*)alloc((size_t)384*384*4);
  float* Bh   = (float*)alloc((size_t)384*256*4);
  float* dinv = (float*)alloc((size_t)NN*4);
  int* deg  = (int*)alloc((size_t)NN*4);
  int* cnt  = (int*)alloc((size_t)NN*4);
  int* cur  = (int*)alloc((size_t)NN*4);
  int* offs = (int*)alloc((size_t)(NN+1)*4);
  int* srcs = (int*)alloc((size_t)EE*4);
  float* wsrt = (float*)alloc((size_t)EE*4);

  const int eb = (EE+255)/256;
  const int nb = (NN+255)/256;
  const int fb = (NN*FF+255)/256;
  const int sg = (NN+3)/4;

  k_pack<<<(384*384+255)/256,256,0,stream>>>(Wxz,Wxr,Wxh,Bx,3);
  k_pack<<<(384*256+255)/256,256,0,stream>>>(Whz,Whr,nullptr,Bh,2);
  k_zero_f<<<fb,256,0,stream>>>(Ha, NN*FF);

  float* Hc = Ha; float* Hn = Hb;
  for(int t=0;t<TT;++t){
    const float* xt = x + (size_t)t*NN*FF;
    const int* src = ei + (size_t)t*2*EE;
    const int* dst = src + EE;
    k_zero2i<<<nb,256,0,stream>>>(deg,cnt,NN);
    k_count<<<eb,256,0,stream>>>(src,dst,deg,cnt);
    k_scan<<<1,1024,0,stream>>>(cnt,deg,offs,dinv,cur);
    k_scatter<<<eb,256,0,stream>>>(src,dst,dinv,offs,cur,srcs,wsrt);
    // Chebyshev propagations: x-path and H-path
    k_spmm<<<sg,256,0,stream>>>(offs,srcs,wsrt, xt, nullptr, A1);
    k_spmm<<<sg,256,0,stream>>>(offs,srcs,wsrt, A1, xt,      A2);
    k_spmm<<<sg,256,0,stream>>>(offs,srcs,wsrt, Hc, nullptr, A3);
    k_spmm<<<sg,256,0,stream>>>(offs,srcs,wsrt, A3, Hc,      A4);
    // fused K=384 GEMMs
    dim3 g1((NN+63)/64, 384/64);
    k_gemm<<<g1,256,0,stream>>>(xt,A1,A2, Bx, OX, 384, 384, 384, 0, 0, nullptr, 0);
    dim3 g2((NN+63)/64, 256/64);
    k_gemm<<<g2,256,0,stream>>>(Hc,A3,A4, Bh, OX, 384, 256, 384, 0, 1, nullptr, 0);
    k_combA<<<fb,256,0,stream>>>(OX,Hc,bxz,bhz,bxr,bhr,Zb,A1);   // A1 <- H*R
    // HR-path propagation + GEMM (accumulates into OX[:,256:384])
    k_spmm<<<sg,256,0,stream>>>(offs,srcs,wsrt, A1, nullptr, A3);
    k_spmm<<<sg,256,0,stream>>>(offs,srcs,wsrt, A3, A1,      A4);
    dim3 g3((NN+63)/64, 128/64);
    k_gemm<<<g3,256,0,stream>>>(A1,A3,A4, Whh, OX, 384, 128, 384, 256, 1, nullptr, 0);
    k_combB<<<fb,256,0,stream>>>(OX,Zb,Hc,bxh,bhh,Hn);
    float* tmp=Hc; Hc=Hn; Hn=tmp;
  }
  // decoder: x_pred = relu(H@Wd1+bd1)@Wd2+bd2
  dim3 gd((NN+63)/64, 2);
  k_gemm<<<gd,256,0,stream>>>(Hc,nullptr,nullptr, Wd1, A2, 128, 128, 128, 0, 0, bd1, 1);
  k_gemm<<<gd,256,0,stream>>>(A2,nullptr,nullptr, Wd2, out, 128, 128, 128, 0, 0, bd2, 0);
  k_copy<<<fb,256,0,stream>>>(Hc, out + (size_t)NN*FF, NN*FF);
}

// Round 2
// 2987.211 us; speedup vs baseline: 1.4083x; 1.4083x over previous
//
#include <hip/hip_runtime.h>
#include <math.h>

#define NN 50000
#define TT 4
#define FF 128
#define EE 800000

typedef __attribute__((ext_vector_type(8))) short bf8_t;
typedef __attribute__((ext_vector_type(4))) float f4_t;
typedef __attribute__((ext_vector_type(8))) ushort us8;

__device__ inline ushort f2bf(float f){
  union { float f; unsigned u; } v; v.f = f;
  unsigned u = v.u;
  unsigned r = (u + 0x7fff + ((u>>16)&1)) >> 16;  // RNE
  return (ushort)r;
}

// ---------------- utility ----------------
__global__ void k_zero_f(float* __restrict__ p, int n){
  int i = blockIdx.x*256 + threadIdx.x;
  if(i<n) p[i]=0.f;
}
__global__ void k_zero2i(int* __restrict__ a, int* __restrict__ b, int n){
  int i = blockIdx.x*256 + threadIdx.x;
  if(i<n){ a[i]=0; b[i]=0; }
}
__global__ void k_copy(const float* __restrict__ a, float* __restrict__ b, int n){
  int i = blockIdx.x*256 + threadIdx.x;
  if(i<n) b[i]=a[i];
}
__global__ void k_cast(const float* __restrict__ in, ushort* __restrict__ outp, int n4){
  int i = blockIdx.x*256 + threadIdx.x;
  if(i<n4){
    float4 v = ((const float4*)in)[i];
    ushort4 o; o.x=f2bf(v.x); o.y=f2bf(v.y); o.z=f2bf(v.z); o.w=f2bf(v.w);
    ((ushort4*)outp)[i]=o;
  }
}

// count out-degree (src) for norm and in-degree (dst) for CSR
__global__ void k_count(const int* __restrict__ src, const int* __restrict__ dst,
                        int* __restrict__ deg, int* __restrict__ cnt){
  int i = blockIdx.x*256 + threadIdx.x;
  if(i<EE){ atomicAdd(&deg[src[i]],1); atomicAdd(&cnt[dst[i]],1); }
}

// single-workgroup scan: offsets (exclusive), dinv, cursor zeroing
__global__ __launch_bounds__(1024) void k_scan(const int* __restrict__ cnt, const int* __restrict__ deg,
                       int* __restrict__ offs, float* __restrict__ dinv, int* __restrict__ cur){
  __shared__ int sd[1024];
  int tid = threadIdx.x;
  int run = 0;
  for(int base=0;base<NN;base+=1024){
    int i = base+tid;
    int c = (i<NN)?cnt[i]:0;
    sd[tid]=c; __syncthreads();
    for(int off=1;off<1024;off<<=1){
      int v = (tid>=off)? sd[tid-off]:0;
      __syncthreads();
      sd[tid]+=v;
      __syncthreads();
    }
    int incl = sd[tid];
    if(i<NN){
      offs[i] = run + incl - c;
      int d = deg[i];
      dinv[i] = d>0 ? rsqrtf((float)d) : 0.f;
      cur[i]=0;
    }
    run += sd[1023];
    __syncthreads();
  }
  if(tid==0) offs[NN] = run;
}

// build dst-sorted CSR of (src, w) pairs
__global__ void k_scatter(const int* __restrict__ src, const int* __restrict__ dst,
                          const float* __restrict__ dinv, const int* __restrict__ offs,
                          int* __restrict__ cur, int* __restrict__ srcs, float* __restrict__ wsrt){
  int i = blockIdx.x*256 + threadIdx.x;
  if(i<EE){
    int s=src[i], d=dst[i];
    float w = -dinv[s]*dinv[d];
    int pos = offs[d] + atomicAdd(&cur[d],1);
    srcs[pos]=s; wsrt[pos]=w;
  }
}

// gather-SpMM: acc[row,:] = sum_e w[e] * X[src[e],:]  (one wave per row, float2/lane)
// if X0 != null: acc = 2*acc - X0[row,:]   (Chebyshev recurrence)
// outputs: outf (fp32, optional), outb (bf16, optional)
__global__ void k_spmm(const int* __restrict__ offs, const int* __restrict__ srcs,
                       const float* __restrict__ wsrt, const float* __restrict__ X,
                       const float* __restrict__ X0, float* __restrict__ outf,
                       ushort* __restrict__ outb){
  int wid = threadIdx.x>>6, lane = threadIdx.x&63;
  int row = blockIdx.x*4+wid;
  if(row>=NN) return;
  int beg = offs[row], end = offs[row+1];
  const float2* X2 = (const float2*)X;
  float ax=0.f, ay=0.f;
  int e = beg;
  for(; e+3<end; e+=4){
    int s0=srcs[e+0], s1=srcs[e+1], s2=srcs[e+2], s3=srcs[e+3];
    float w0=wsrt[e+0], w1=wsrt[e+1], w2=wsrt[e+2], w3=wsrt[e+3];
    float2 v0=X2[s0*64+lane], v1=X2[s1*64+lane], v2=X2[s2*64+lane], v3=X2[s3*64+lane];
    ax = fmaf(w0,v0.x,ax); ay = fmaf(w0,v0.y,ay);
    ax = fmaf(w1,v1.x,ax); ay = fmaf(w1,v1.y,ay);
    ax = fmaf(w2,v2.x,ax); ay = fmaf(w2,v2.y,ay);
    ax = fmaf(w3,v3.x,ax); ay = fmaf(w3,v3.y,ay);
  }
  for(; e<end; ++e){
    int s=srcs[e]; float w=wsrt[e];
    float2 v=X2[s*64+lane];
    ax = fmaf(w,v.x,ax); ay = fmaf(w,v.y,ay);
  }
  int oi = row*64+lane;
  if(X0){
    float2 x0 = ((const float2*)X0)[oi];
    ax = 2.f*ax - x0.x; ay = 2.f*ay - x0.y;
  }
  if(outf){ float2 r; r.x=ax; r.y=ay; ((float2*)outf)[oi]=r; }
  if(outb){ ushort2 h; h.x=f2bf(ax); h.y=f2bf(ay); ((ushort2*)outb)[oi]=h; }
}

// ---------------- MFMA bf16 GEMM ----------------
// C[r, coloff+c] (+)= sum_k A[r,k]*B[k,c]; A given as up-to-6 chunks of 128 bf16 cols,
// B given TRANSPOSED: Bt[c][k] bf16, row stride K. 128x128 tile, BK=64, 4 waves.
// LDS XOR-swizzle (row&7)<<4 on both write and read (G4 / rule #21).
__global__ __launch_bounds__(256) void k_mgemm(
    const ushort* __restrict__ A0, const ushort* __restrict__ A1,
    const ushort* __restrict__ A2, const ushort* __restrict__ A3,
    const ushort* __restrict__ A4, const ushort* __restrict__ A5,
    const ushort* __restrict__ Bt, float* __restrict__ C,
    int K, int ldc, int coloff, int beta)
{
  __shared__ ushort As[128*64];
  __shared__ ushort Bs[128*64];
  int tid = threadIdx.x;
  int lane = tid & 63;
  int wid = tid >> 6;
  int wr = (wid>>1)*64, wc = (wid&1)*64;
  int bm = blockIdx.x, bn = blockIdx.y;
  f4_t acc[4][4] = {};
  int srow = tid>>3, sc = tid&7;
  int lr = lane&15, lk = lane>>4;
  int nkt = K>>6;
  for(int kt=0; kt<nkt; ++kt){
    int k0 = kt<<6;
    const ushort* Ac = (k0<128)?A0:(k0<256)?A1:(k0<384)?A2:(k0<512)?A3:(k0<640)?A4:A5;
    int kloc = k0 & 127;   // 0 or 64 within chunk
    #pragma unroll
    for(int p=0;p<4;++p){
      int r = srow + p*32;
      int gr = bm*128 + r; if(gr>=NN) gr=NN-1;
      us8 av = *(const us8*)(Ac + (size_t)gr*128 + kloc + sc*8);
      us8 bv = *(const us8*)(Bt + (size_t)(bn*128 + r)*K + k0 + sc*8);
      int wo = (r*128 + ((sc*16) ^ ((r&7)<<4))) >> 1;  // ushort index, swizzled
      *(us8*)(As + wo) = av;
      *(us8*)(Bs + wo) = bv;
    }
    __syncthreads();
    #pragma unroll
    for(int kk=0;kk<2;++kk){
      bf8_t af[4], bfr[4];
      int co = kk*64 + lk*16;   // byte offset within 128B row, pre-swizzle
      #pragma unroll
      for(int m=0;m<4;++m){
        int Ra = wr + m*16 + lr;
        af[m]  = *(const bf8_t*)(As + ((Ra*128 + (co ^ ((Ra&7)<<4)))>>1));
        int Rb = wc + m*16 + lr;
        bfr[m] = *(const bf8_t*)(Bs + ((Rb*128 + (co ^ ((Rb&7)<<4)))>>1));
      }
      #pragma unroll
      for(int m=0;m<4;++m)
        #pragma unroll
        for(int n=0;n<4;++n)
          acc[m][n] = __builtin_amdgcn_mfma_f32_16x16x32_bf16(af[m], bfr[n], acc[m][n], 0,0,0);
    }
    __syncthreads();
  }
  // epilogue: D frag row=(lane>>4)*4+i, col=lane&15  [m89]
  int row0 = bm*128 + wr + lk*4;
  int col0 = coloff + bn*128 + wc + lr;
  #pragma unroll
  for(int m=0;m<4;++m){
    #pragma unroll
    for(int i=0;i<4;++i){
      int r = row0 + m*16 + i;
      if(r<NN){
        float* cp = C + (size_t)r*ldc + col0;
        #pragma unroll
        for(int n=0;n<4;++n){
          float v = acc[m][n][i];
          if(beta) v += cp[n*16];
          cp[n*16] = v;
        }
      }
    }
  }
}

// fp32 GEMM kept for the (small) decoder
__global__ __launch_bounds__(256) void k_gemm(
    const float* __restrict__ A0, const float* __restrict__ A1, const float* __restrict__ A2,
    const float* __restrict__ B, float* __restrict__ C,
    int K, int Fo, int ldc, int coloff, int beta,
    const float* __restrict__ bias, int act){
  __shared__ float Asq[64][17];
  __shared__ float Bsq[16][64];
  int tid = threadIdx.x;
  int tx = tid & 15, ty = tid >> 4;
  int bm = blockIdx.x, bn = blockIdx.y;
  float acc[4][4] = {{0.f}};
  int lr = tid>>2, lkv = tid&3;
  int lkk = tid>>4, lcv = tid&15;
  int arow = bm*64 + lr; if(arow >= NN) arow = NN-1;
  int nkb = K>>4;
  for(int kb=0; kb<nkb; ++kb){
    int koff = kb<<4;
    const float* Ac = (koff<128)?A0:((koff<256)?A1:A2);
    int kloc = koff & 127;
    float4 av = *(const float4*)(Ac + arow*128 + kloc + lkv*4);
    float4 bv = *(const float4*)(B + (koff+lkk)*Fo + bn*64 + lcv*4);
    Asq[lr][lkv*4+0]=av.x; Asq[lr][lkv*4+1]=av.y; Asq[lr][lkv*4+2]=av.z; Asq[lr][lkv*4+3]=av.w;
    *(float4*)(&Bsq[lkk][lcv*4]) = bv;
    __syncthreads();
    #pragma unroll
    for(int kk=0;kk<16;++kk){
      float a0=Asq[ty*4+0][kk], a1=Asq[ty*4+1][kk], a2=Asq[ty*4+2][kk], a3=Asq[ty*4+3][kk];
      float4 b = *(const float4*)(&Bsq[kk][tx*4]);
      acc[0][0]=fmaf(a0,b.x,acc[0][0]); acc[0][1]=fmaf(a0,b.y,acc[0][1]);
      acc[0][2]=fmaf(a0,b.z,acc[0][2]); acc[0][3]=fmaf(a0,b.w,acc[0][3]);
      acc[1][0]=fmaf(a1,b.x,acc[1][0]); acc[1][1]=fmaf(a1,b.y,acc[1][1]);
      acc[1][2]=fmaf(a1,b.z,acc[1][2]); acc[1][3]=fmaf(a1,b.w,acc[1][3]);
      acc[2][0]=fmaf(a2,b.x,acc[2][0]); acc[2][1]=fmaf(a2,b.y,acc[2][1]);
      acc[2][2]=fmaf(a2,b.z,acc[2][2]); acc[2][3]=fmaf(a2,b.w,acc[2][3]);
      acc[3][0]=fmaf(a3,b.x,acc[3][0]); acc[3][1]=fmaf(a3,b.y,acc[3][1]);
      acc[3][2]=fmaf(a3,b.z,acc[3][2]); acc[3][3]=fmaf(a3,b.w,acc[3][3]);
    }
    __syncthreads();
  }
  int row0 = bm*64 + ty*4;
  int col  = bn*64 + tx*4;
  #pragma unroll
  for(int i=0;i<4;++i){
    int r = row0+i;
    if(r<NN){
      float4 v; v.x=acc[i][0]; v.y=acc[i][1]; v.z=acc[i][2]; v.w=acc[i][3];
      if(bias){ v.x+=bias[col]; v.y+=bias[col+1]; v.z+=bias[col+2]; v.w+=bias[col+3]; }
      if(act){ v.x=fmaxf(v.x,0.f); v.y=fmaxf(v.y,0.f); v.z=fmaxf(v.z,0.f); v.w=fmaxf(v.w,0.f); }
      float* cp = C + r*ldc + coloff + col;
      if(beta){ float4 o=*(const float4*)cp; v.x+=o.x; v.y+=o.y; v.z+=o.z; v.w+=o.w; }
      *(float4*)cp = v;
    }
  }
}

// Z = sigmoid(OX[:,0:128]+bxz+bhz); HR = H * sigmoid(OX[:,128:256]+bxr+bhr)
__global__ void k_combA(const float* __restrict__ OX, const float* __restrict__ H,
                        const float* __restrict__ bxz, const float* __restrict__ bhz,
                        const float* __restrict__ bxr, const float* __restrict__ bhr,
                        float* __restrict__ Z, float* __restrict__ HR,
                        ushort* __restrict__ HRb){
  int i = blockIdx.x*256 + threadIdx.x;
  if(i>=NN*FF) return;
  int r = i>>7, c = i&127;
  float zv = OX[r*384+c]     + bxz[c] + bhz[c];
  float rv = OX[r*384+128+c] + bxr[c] + bhr[c];
  zv = 1.f/(1.f+expf(-zv));
  rv = 1.f/(1.f+expf(-rv));
  float hr = H[i]*rv;
  Z[i]=zv; HR[i]=hr; HRb[i]=f2bf(hr);
}

// Htilde = tanh(OX[:,256:384]+bxh+bhh); Hnew = Z*H + (1-Z)*Htilde
__global__ void k_combB(const float* __restrict__ OX, const float* __restrict__ Z,
                        const float* __restrict__ H, const float* __restrict__ bxh,
                        const float* __restrict__ bhh, float* __restrict__ Hn,
                        ushort* __restrict__ Hnb){
  int i = blockIdx.x*256 + threadIdx.x;
  if(i>=NN*FF) return;
  int r = i>>7, c = i&127;
  float ht = tanhf(OX[r*384+256+c] + bxh[c] + bhh[c]);
  float z = Z[i];
  float hn = z*H[i] + (1.f-z)*ht;
  Hn[i] = hn; Hnb[i] = f2bf(hn);
}

// pack x-side weights transposed+concatenated: Btx[c][k], c in [0,384), k in [0,768)
// k-chunks 0..2 -> Wx{z,r,h}[kb]; 3..5 -> Wh{z,r}[kb-3] for gates z,r; 0 for gate h.
__global__ void k_packx(const float* __restrict__ Wxz, const float* __restrict__ Wxr,
                        const float* __restrict__ Wxh, const float* __restrict__ Whz,
                        const float* __restrict__ Whr, ushort* __restrict__ Bt){
  int i = blockIdx.x*256 + threadIdx.x;
  if(i>=384*768) return;
  int c = i/768, k = i - c*768;
  int g = c>>7, j = c&127;
  int kb = k>>7, kk = k&127;
  float v;
  if(kb<3){
    const float* W = (g==0)?Wxz:((g==1)?Wxr:Wxh);
    v = W[(kb*128+kk)*128 + j];
  } else if(g<2){
    const float* W = (g==0)?Whz:Whr;
    v = W[((kb-3)*128+kk)*128 + j];
  } else v = 0.f;
  Bt[i] = f2bf(v);
}
// Bth[c][k] = Whh[k>>7][k&127][c], c<128, k<384
__global__ void k_packh(const float* __restrict__ Whh, ushort* __restrict__ Bt){
  int i = blockIdx.x*256 + threadIdx.x;
  if(i>=128*384) return;
  int c = i/384, k = i - c*384;
  Bt[i] = f2bf(Whh[((k>>7)*128 + (k&127))*128 + c]);
}

extern "C" void kernel_launch(void* const* d_in, const int* in_sizes, int n_in,
                              void* d_out, int out_size, void* d_ws, size_t ws_size,
                              hipStream_t stream) {
  const float* x   = (const float*)d_in[0];
  const int*   ei  = (const int*)d_in[1];
  const float* Wxz = (const float*)d_in[2];
  const float* Whz = (const float*)d_in[3];
  const float* Wxr = (const float*)d_in[4];
  const float* Whr = (const float*)d_in[5];
  const float* Wxh = (const float*)d_in[6];
  const float* Whh = (const float*)d_in[7];
  const float* bxz = (const float*)d_in[8];
  const float* bhz = (const float*)d_in[9];
  const float* bxr = (const float*)d_in[10];
  const float* bhr = (const float*)d_in[11];
  const float* bxh = (const float*)d_in[12];
  const float* bhh = (const float*)d_in[13];
  const float* Wd1 = (const float*)d_in[14];
  const float* bd1 = (const float*)d_in[15];
  const float* Wd2 = (const float*)d_in[16];
  const float* bd2 = (const float*)d_in[17];
  float* out = (float*)d_out;

  char* p = (char*)d_ws;
  auto alloc = [&](size_t bytes)->void*{ void* r = (void*)p; p += (bytes+255)&~(size_t)255; return r; };
  const size_t NFB  = (size_t)NN*FF*4;   // fp32 N x 128
  const size_t NFB2 = (size_t)NN*FF*2;   // bf16 N x 128
  float* Ha   = (float*)alloc(NFB);
  float* Hb   = (float*)alloc(NFB);
  float* A1f  = (float*)alloc(NFB);      // T1 fp32 / later HR fp32
  float* A3f  = (float*)alloc(NFB);      // T1 fp32 (H / HR path)
  float* OX   = (float*)alloc((size_t)NN*384*4);
  float* Zb   = (float*)alloc(NFB);      // Z / decoder temp
  ushort* xtb = (ushort*)alloc(NFB2);
  ushort* A1b = (ushort*)alloc(NFB2);
  ushort* A2b = (ushort*)alloc(NFB2);
  ushort* A3b = (ushort*)alloc(NFB2);
  ushort* A4b = (ushort*)alloc(NFB2);
  ushort* HRb = (ushort*)alloc(NFB2);
  ushort* Hab = (ushort*)alloc(NFB2);
  ushort* Hbb = (ushort*)alloc(NFB2);
  ushort* Btx = (ushort*)alloc((size_t)384*768*2);
  ushort* Bth = (ushort*)alloc((size_t)128*384*2);
  float* dinv = (float*)alloc((size_t)NN*4);
  int* deg  = (int*)alloc((size_t)NN*4);
  int* cnt  = (int*)alloc((size_t)NN*4);
  int* cur  = (int*)alloc((size_t)NN*4);
  int* offs = (int*)alloc((size_t)(NN+1)*4);
  int* srcs = (int*)alloc((size_t)EE*4);
  float* wsrt = (float*)alloc((size_t)EE*4);

  const int eb = (EE+255)/256;
  const int nb = (NN+255)/256;
  const int fb = (NN*FF+255)/256;
  const int sg = (NN+3)/4;
  const int MT = (NN+127)/128;  // 391

  k_packx<<<(384*768+255)/256,256,0,stream>>>(Wxz,Wxr,Wxh,Whz,Whr,Btx);
  k_packh<<<(128*384+255)/256,256,0,stream>>>(Whh,Bth);
  k_zero_f<<<fb,256,0,stream>>>(Ha, NN*FF);
  k_zero_f<<<(NN*FF/2+255)/256,256,0,stream>>>((float*)Hab, NN*FF/2);  // bf16 zeros

  float* Hc = Ha; float* Hn = Hb;
  ushort* Hcb = Hab; ushort* Hnb = Hbb;
  for(int t=0;t<TT;++t){
    const float* xt = x + (size_t)t*NN*FF;
    const int* src = ei + (size_t)t*2*EE;
    const int* dst = src + EE;
    k_cast<<<(NN*FF/4+255)/256,256,0,stream>>>(xt, xtb, NN*FF/4);
    k_zero2i<<<nb,256,0,stream>>>(deg,cnt,NN);
    k_count<<<eb,256,0,stream>>>(src,dst,deg,cnt);
    k_scan<<<1,1024,0,stream>>>(cnt,deg,offs,dinv,cur);
    k_scatter<<<eb,256,0,stream>>>(src,dst,dinv,offs,cur,srcs,wsrt);
    // Chebyshev propagations: x-path and H-path (T2 outputs bf16-only)
    k_spmm<<<sg,256,0,stream>>>(offs,srcs,wsrt, xt,  nullptr, A1f, A1b);
    k_spmm<<<sg,256,0,stream>>>(offs,srcs,wsrt, A1f, xt,      nullptr, A2b);
    k_spmm<<<sg,256,0,stream>>>(offs,srcs,wsrt, Hc,  nullptr, A3f, A3b);
    k_spmm<<<sg,256,0,stream>>>(offs,srcs,wsrt, A3f, Hc,      nullptr, A4b);
    // fused K=768 MFMA GEMM -> OX[:,0:384]
    dim3 g1(MT, 3);
    k_mgemm<<<g1,256,0,stream>>>(xtb,A1b,A2b,Hcb,A3b,A4b, Btx, OX, 768, 384, 0, 0);
    k_combA<<<fb,256,0,stream>>>(OX,Hc,bxz,bhz,bxr,bhr,Zb,A1f,HRb);   // A1f <- H*R fp32
    // HR-path propagation + K=384 MFMA GEMM (accumulates into OX[:,256:384])
    k_spmm<<<sg,256,0,stream>>>(offs,srcs,wsrt, A1f, nullptr, A3f, A3b);
    k_spmm<<<sg,256,0,stream>>>(offs,srcs,wsrt, A3f, A1f,     nullptr, A4b);
    dim3 g3(MT, 1);
    k_mgemm<<<g3,256,0,stream>>>(HRb,A3b,A4b,nullptr,nullptr,nullptr, Bth, OX, 384, 384, 256, 1);
    k_combB<<<fb,256,0,stream>>>(OX,Zb,Hc,bxh,bhh,Hn,Hnb);
    float* tmp=Hc; Hc=Hn; Hn=tmp;
    ushort* tb=Hcb; Hcb=Hnb; Hnb=tb;
  }
  // decoder: x_pred = relu(H@Wd1+bd1)@Wd2+bd2  (fp32)
  dim3 gd((NN+63)/64, 2);
  k_gemm<<<gd,256,0,stream>>>(Hc,nullptr,nullptr, Wd1, Zb, 128, 128, 128, 0, 0, bd1, 1);
  k_gemm<<<gd,256,0,stream>>>(Zb,nullptr,nullptr, Wd2, out, 128, 128, 128, 0, 0, bd2, 0);
  k_copy<<<fb,256,0,stream>>>(Hc, out + (size_t)NN*FF, NN*FF);
}

// Round 3
// 1857.854 us; speedup vs baseline: 2.2644x; 1.6079x over previous
//
#include <hip/hip_runtime.h>
#include <math.h>

#define NN 50000
#define TT 4
#define FF 128
#define EE 800000
#define NBS 196   // scan blocks = ceil(NN/256)

typedef __attribute__((ext_vector_type(8))) short bf8_t;
typedef __attribute__((ext_vector_type(4))) float f4_t;
typedef __attribute__((ext_vector_type(8))) ushort us8;

__device__ inline ushort f2bf(float f){
  union { float f; unsigned u; } v; v.f = f;
  unsigned u = v.u;
  unsigned r = (u + 0x7fff + ((u>>16)&1)) >> 16;  // RNE
  return (ushort)r;
}
__device__ inline float lo16(unsigned u){ union{unsigned u;float f;}v; v.u=u<<16; return v.f; }
__device__ inline float hi16(unsigned u){ union{unsigned u;float f;}v; v.u=u&0xffff0000u; return v.f; }
__device__ inline unsigned packbf(float x, float y){
  return (unsigned)f2bf(x) | ((unsigned)f2bf(y)<<16);
}

// ---------------- utility ----------------
__global__ void k_zero_f(float* __restrict__ p, int n){
  int i = blockIdx.x*256 + threadIdx.x;
  if(i<n) p[i]=0.f;
}
__global__ void k_zero2i(int* __restrict__ a, int* __restrict__ b, int n){
  int i = blockIdx.x*256 + threadIdx.x;
  if(i<n){ a[i]=0; b[i]=0; }
}
__global__ void k_copy(const float* __restrict__ a, float* __restrict__ b, int n){
  int i = blockIdx.x*256 + threadIdx.x;
  if(i<n) b[i]=a[i];
}
__global__ void k_cast(const float* __restrict__ in, ushort* __restrict__ outp, int n4){
  int i = blockIdx.x*256 + threadIdx.x;
  if(i<n4){
    float4 v = ((const float4*)in)[i];
    ushort4 o; o.x=f2bf(v.x); o.y=f2bf(v.y); o.z=f2bf(v.z); o.w=f2bf(v.w);
    ((ushort4*)outp)[i]=o;
  }
}

// count out-degree (src) for norm and in-degree (dst) for CSR
__global__ void k_count(const int* __restrict__ src, const int* __restrict__ dst,
                        int* __restrict__ deg, int* __restrict__ cnt){
  int i = blockIdx.x*256 + threadIdx.x;
  if(i<EE){ atomicAdd(&deg[src[i]],1); atomicAdd(&cnt[dst[i]],1); }
}

// ---------- hierarchical exclusive scan over cnt -> offs ----------
__global__ void k_scanA(const int* __restrict__ cnt, int* __restrict__ offs,
                        int* __restrict__ part){
  __shared__ int sd[256];
  int b = blockIdx.x, tid = threadIdx.x, i = b*256+tid;
  int c = (i<NN)?cnt[i]:0;
  sd[tid]=c; __syncthreads();
  for(int off=1;off<256;off<<=1){
    int v=(tid>=off)?sd[tid-off]:0; __syncthreads();
    sd[tid]+=v; __syncthreads();
  }
  if(i<NN) offs[i]=sd[tid]-c;     // within-block exclusive
  if(tid==255) part[b]=sd[255];
}
__global__ void k_scanB(int* __restrict__ part){   // one block
  __shared__ int sd[256];
  int tid = threadIdx.x;
  int v = (tid<NBS)?part[tid]:0;
  sd[tid]=v; __syncthreads();
  for(int off=1;off<256;off<<=1){
    int t=(tid>=off)?sd[tid-off]:0; __syncthreads();
    sd[tid]+=t; __syncthreads();
  }
  if(tid<NBS) part[tid]=sd[tid]-v;  // exclusive block bases
}
__global__ void k_scanC(const int* __restrict__ deg, int* __restrict__ offs,
                        const int* __restrict__ part, float* __restrict__ dinv,
                        int* __restrict__ cur){
  int i = blockIdx.x*256 + threadIdx.x;
  if(i<NN){
    offs[i] += part[blockIdx.x];
    int d = deg[i];
    dinv[i] = d>0 ? rsqrtf((float)d) : 0.f;
    cur[i]=0;
  }
  if(i==0) offs[NN]=EE;
}

// build dst-sorted CSR of (src, w) pairs
__global__ void k_scatter(const int* __restrict__ src, const int* __restrict__ dst,
                          const float* __restrict__ dinv, const int* __restrict__ offs,
                          int* __restrict__ cur, int* __restrict__ srcs, float* __restrict__ wsrt){
  int i = blockIdx.x*256 + threadIdx.x;
  if(i<EE){
    int s=src[i], d=dst[i];
    float w = -dinv[s]*dinv[d];
    int pos = offs[d] + atomicAdd(&cur[d],1);
    srcs[pos]=s; wsrt[pos]=w;
  }
}

// -------- fused dual-input bf16 gather-SpMM (one wave per row, uint=2xbf16 per lane) --------
// outA = [2*]L@Xa[-X0a], outB = [2*]L@Xb[-X0b]   (recurrence if X0 given)
__global__ void k_spmm2(const int* __restrict__ offs, const int* __restrict__ srcs,
                        const float* __restrict__ wsrt,
                        const ushort* __restrict__ Xa, const ushort* __restrict__ Xb,
                        const ushort* __restrict__ X0a, const ushort* __restrict__ X0b,
                        ushort* __restrict__ outA, ushort* __restrict__ outB){
  int wid = threadIdx.x>>6, lane = threadIdx.x&63;
  int row = blockIdx.x*4+wid;
  if(row>=NN) return;
  int beg = offs[row], end = offs[row+1];
  const unsigned* XA = (const unsigned*)Xa;
  const unsigned* XB = (const unsigned*)Xb;
  float ax=0.f, ay=0.f, bx=0.f, by=0.f;
  int e = beg;
  for(; e+3<end; e+=4){
    int s0=srcs[e+0], s1=srcs[e+1], s2=srcs[e+2], s3=srcs[e+3];
    float w0=wsrt[e+0], w1=wsrt[e+1], w2=wsrt[e+2], w3=wsrt[e+3];
    unsigned a0=XA[s0*64+lane], a1=XA[s1*64+lane], a2=XA[s2*64+lane], a3=XA[s3*64+lane];
    unsigned b0=XB[s0*64+lane], b1=XB[s1*64+lane], b2=XB[s2*64+lane], b3=XB[s3*64+lane];
    ax=fmaf(w0,lo16(a0),ax); ay=fmaf(w0,hi16(a0),ay);
    ax=fmaf(w1,lo16(a1),ax); ay=fmaf(w1,hi16(a1),ay);
    ax=fmaf(w2,lo16(a2),ax); ay=fmaf(w2,hi16(a2),ay);
    ax=fmaf(w3,lo16(a3),ax); ay=fmaf(w3,hi16(a3),ay);
    bx=fmaf(w0,lo16(b0),bx); by=fmaf(w0,hi16(b0),by);
    bx=fmaf(w1,lo16(b1),bx); by=fmaf(w1,hi16(b1),by);
    bx=fmaf(w2,lo16(b2),bx); by=fmaf(w2,hi16(b2),by);
    bx=fmaf(w3,lo16(b3),bx); by=fmaf(w3,hi16(b3),by);
  }
  for(; e<end; ++e){
    int s=srcs[e]; float w=wsrt[e];
    unsigned a=XA[s*64+lane], b=XB[s*64+lane];
    ax=fmaf(w,lo16(a),ax); ay=fmaf(w,hi16(a),ay);
    bx=fmaf(w,lo16(b),bx); by=fmaf(w,hi16(b),by);
  }
  int oi = row*64+lane;
  if(X0a){
    unsigned xa = ((const unsigned*)X0a)[oi];
    unsigned xb = ((const unsigned*)X0b)[oi];
    ax = 2.f*ax - lo16(xa); ay = 2.f*ay - hi16(xa);
    bx = 2.f*bx - lo16(xb); by = 2.f*by - hi16(xb);
  }
  ((unsigned*)outA)[oi] = packbf(ax, ay);
  ((unsigned*)outB)[oi] = packbf(bx, by);
}

// single-input variant (HR path)
__global__ void k_spmm1(const int* __restrict__ offs, const int* __restrict__ srcs,
                        const float* __restrict__ wsrt,
                        const ushort* __restrict__ Xa, const ushort* __restrict__ X0a,
                        ushort* __restrict__ outA){
  int wid = threadIdx.x>>6, lane = threadIdx.x&63;
  int row = blockIdx.x*4+wid;
  if(row>=NN) return;
  int beg = offs[row], end = offs[row+1];
  const unsigned* XA = (const unsigned*)Xa;
  float ax=0.f, ay=0.f;
  int e = beg;
  for(; e+3<end; e+=4){
    int s0=srcs[e+0], s1=srcs[e+1], s2=srcs[e+2], s3=srcs[e+3];
    float w0=wsrt[e+0], w1=wsrt[e+1], w2=wsrt[e+2], w3=wsrt[e+3];
    unsigned a0=XA[s0*64+lane], a1=XA[s1*64+lane], a2=XA[s2*64+lane], a3=XA[s3*64+lane];
    ax=fmaf(w0,lo16(a0),ax); ay=fmaf(w0,hi16(a0),ay);
    ax=fmaf(w1,lo16(a1),ax); ay=fmaf(w1,hi16(a1),ay);
    ax=fmaf(w2,lo16(a2),ax); ay=fmaf(w2,hi16(a2),ay);
    ax=fmaf(w3,lo16(a3),ax); ay=fmaf(w3,hi16(a3),ay);
  }
  for(; e<end; ++e){
    int s=srcs[e]; float w=wsrt[e];
    unsigned a=XA[s*64+lane];
    ax=fmaf(w,lo16(a),ax); ay=fmaf(w,hi16(a),ay);
  }
  int oi = row*64+lane;
  if(X0a){
    unsigned xa = ((const unsigned*)X0a)[oi];
    ax = 2.f*ax - lo16(xa); ay = 2.f*ay - hi16(xa);
  }
  ((unsigned*)outA)[oi] = packbf(ax, ay);
}

// ---------------- MFMA bf16 GEMM ----------------
__global__ __launch_bounds__(256) void k_mgemm(
    const ushort* __restrict__ A0, const ushort* __restrict__ A1,
    const ushort* __restrict__ A2, const ushort* __restrict__ A3,
    const ushort* __restrict__ A4, const ushort* __restrict__ A5,
    const ushort* __restrict__ Bt, float* __restrict__ C,
    int K, int ldc, int coloff, int beta)
{
  __shared__ ushort As[128*64];
  __shared__ ushort Bs[128*64];
  int tid = threadIdx.x;
  int lane = tid & 63;
  int wid = tid >> 6;
  int wr = (wid>>1)*64, wc = (wid&1)*64;
  int bm = blockIdx.x, bn = blockIdx.y;
  f4_t acc[4][4] = {};
  int srow = tid>>3, sc = tid&7;
  int lr = lane&15, lk = lane>>4;
  int nkt = K>>6;
  for(int kt=0; kt<nkt; ++kt){
    int k0 = kt<<6;
    const ushort* Ac = (k0<128)?A0:(k0<256)?A1:(k0<384)?A2:(k0<512)?A3:(k0<640)?A4:A5;
    int kloc = k0 & 127;   // 0 or 64 within chunk
    #pragma unroll
    for(int p=0;p<4;++p){
      int r = srow + p*32;
      int gr = bm*128 + r; if(gr>=NN) gr=NN-1;
      us8 av = *(const us8*)(Ac + (size_t)gr*128 + kloc + sc*8);
      us8 bv = *(const us8*)(Bt + (size_t)(bn*128 + r)*K + k0 + sc*8);
      int wo = (r*128 + ((sc*16) ^ ((r&7)<<4))) >> 1;  // ushort index, swizzled
      *(us8*)(As + wo) = av;
      *(us8*)(Bs + wo) = bv;
    }
    __syncthreads();
    #pragma unroll
    for(int kk=0;kk<2;++kk){
      bf8_t af[4], bfr[4];
      int co = kk*64 + lk*16;
      #pragma unroll
      for(int m=0;m<4;++m){
        int Ra = wr + m*16 + lr;
        af[m]  = *(const bf8_t*)(As + ((Ra*128 + (co ^ ((Ra&7)<<4)))>>1));
        int Rb = wc + m*16 + lr;
        bfr[m] = *(const bf8_t*)(Bs + ((Rb*128 + (co ^ ((Rb&7)<<4)))>>1));
      }
      #pragma unroll
      for(int m=0;m<4;++m)
        #pragma unroll
        for(int n=0;n<4;++n)
          acc[m][n] = __builtin_amdgcn_mfma_f32_16x16x32_bf16(af[m], bfr[n], acc[m][n], 0,0,0);
    }
    __syncthreads();
  }
  int row0 = bm*128 + wr + lk*4;
  int col0 = coloff + bn*128 + wc + lr;
  #pragma unroll
  for(int m=0;m<4;++m){
    #pragma unroll
    for(int i=0;i<4;++i){
      int r = row0 + m*16 + i;
      if(r<NN){
        float* cp = C + (size_t)r*ldc + col0;
        #pragma unroll
        for(int n=0;n<4;++n){
          float v = acc[m][n][i];
          if(beta) v += cp[n*16];
          cp[n*16] = v;
        }
      }
    }
  }
}

// fp32 GEMM kept for the (small) decoder
__global__ __launch_bounds__(256) void k_gemm(
    const float* __restrict__ A0, const float* __restrict__ B, float* __restrict__ C,
    int K, int Fo, int ldc, const float* __restrict__ bias, int act){
  __shared__ float Asq[64][17];
  __shared__ float Bsq[16][64];
  int tid = threadIdx.x;
  int tx = tid & 15, ty = tid >> 4;
  int bm = blockIdx.x, bn = blockIdx.y;
  float acc[4][4] = {{0.f}};
  int lr = tid>>2, lkv = tid&3;
  int lkk = tid>>4, lcv = tid&15;
  int arow = bm*64 + lr; if(arow >= NN) arow = NN-1;
  int nkb = K>>4;
  for(int kb=0; kb<nkb; ++kb){
    int koff = kb<<4;
    float4 av = *(const float4*)(A0 + arow*128 + koff + lkv*4);
    float4 bv = *(const float4*)(B + (koff+lkk)*Fo + bn*64 + lcv*4);
    Asq[lr][lkv*4+0]=av.x; Asq[lr][lkv*4+1]=av.y; Asq[lr][lkv*4+2]=av.z; Asq[lr][lkv*4+3]=av.w;
    *(float4*)(&Bsq[lkk][lcv*4]) = bv;
    __syncthreads();
    #pragma unroll
    for(int kk=0;kk<16;++kk){
      float a0=Asq[ty*4+0][kk], a1=Asq[ty*4+1][kk], a2=Asq[ty*4+2][kk], a3=Asq[ty*4+3][kk];
      float4 b = *(const float4*)(&Bsq[kk][tx*4]);
      acc[0][0]=fmaf(a0,b.x,acc[0][0]); acc[0][1]=fmaf(a0,b.y,acc[0][1]);
      acc[0][2]=fmaf(a0,b.z,acc[0][2]); acc[0][3]=fmaf(a0,b.w,acc[0][3]);
      acc[1][0]=fmaf(a1,b.x,acc[1][0]); acc[1][1]=fmaf(a1,b.y,acc[1][1]);
      acc[1][2]=fmaf(a1,b.z,acc[1][2]); acc[1][3]=fmaf(a1,b.w,acc[1][3]);
      acc[2][0]=fmaf(a2,b.x,acc[2][0]); acc[2][1]=fmaf(a2,b.y,acc[2][1]);
      acc[2][2]=fmaf(a2,b.z,acc[2][2]); acc[2][3]=fmaf(a2,b.w,acc[2][3]);
      acc[3][0]=fmaf(a3,b.x,acc[3][0]); acc[3][1]=fmaf(a3,b.y,acc[3][1]);
      acc[3][2]=fmaf(a3,b.z,acc[3][2]); acc[3][3]=fmaf(a3,b.w,acc[3][3]);
    }
    __syncthreads();
  }
  int row0 = bm*64 + ty*4;
  int col  = bn*64 + tx*4;
  #pragma unroll
  for(int i=0;i<4;++i){
    int r = row0+i;
    if(r<NN){
      float4 v; v.x=acc[i][0]; v.y=acc[i][1]; v.z=acc[i][2]; v.w=acc[i][3];
      if(bias){ v.x+=bias[col]; v.y+=bias[col+1]; v.z+=bias[col+2]; v.w+=bias[col+3]; }
      if(act){ v.x=fmaxf(v.x,0.f); v.y=fmaxf(v.y,0.f); v.z=fmaxf(v.z,0.f); v.w=fmaxf(v.w,0.f); }
      float* cp = C + r*ldc + col;
      *(float4*)cp = v;
    }
  }
}

// Z = sigmoid(OX[:,0:128]+bxz+bhz); HRb = bf16(H * sigmoid(OX[:,128:256]+bxr+bhr))
__global__ void k_combA(const float* __restrict__ OX, const float* __restrict__ H,
                        const float* __restrict__ bxz, const float* __restrict__ bhz,
                        const float* __restrict__ bxr, const float* __restrict__ bhr,
                        float* __restrict__ Z, ushort* __restrict__ HRb){
  int i = blockIdx.x*256 + threadIdx.x;
  if(i>=NN*FF) return;
  int r = i>>7, c = i&127;
  float zv = OX[r*384+c]     + bxz[c] + bhz[c];
  float rv = OX[r*384+128+c] + bxr[c] + bhr[c];
  zv = 1.f/(1.f+expf(-zv));
  rv = 1.f/(1.f+expf(-rv));
  float hr = H[i]*rv;
  Z[i]=zv; HRb[i]=f2bf(hr);
}

// Htilde = tanh(OX[:,256:384]+bxh+bhh); Hnew = Z*H + (1-Z)*Htilde
__global__ void k_combB(const float* __restrict__ OX, const float* __restrict__ Z,
                        const float* __restrict__ H, const float* __restrict__ bxh,
                        const float* __restrict__ bhh, float* __restrict__ Hn,
                        ushort* __restrict__ Hnb){
  int i = blockIdx.x*256 + threadIdx.x;
  if(i>=NN*FF) return;
  int r = i>>7, c = i&127;
  float ht = tanhf(OX[r*384+256+c] + bxh[c] + bhh[c]);
  float z = Z[i];
  float hn = z*H[i] + (1.f-z)*ht;
  Hn[i] = hn; Hnb[i] = f2bf(hn);
}

// pack x-side weights transposed+concatenated: Btx[c][k], c in [0,384), k in [0,768)
__global__ void k_packx(const float* __restrict__ Wxz, const float* __restrict__ Wxr,
                        const float* __restrict__ Wxh, const float* __restrict__ Whz,
                        const float* __restrict__ Whr, ushort* __restrict__ Bt){
  int i = blockIdx.x*256 + threadIdx.x;
  if(i>=384*768) return;
  int c = i/768, k = i - c*768;
  int g = c>>7, j = c&127;
  int kb = k>>7, kk = k&127;
  float v;
  if(kb<3){
    const float* W = (g==0)?Wxz:((g==1)?Wxr:Wxh);
    v = W[(kb*128+kk)*128 + j];
  } else if(g<2){
    const float* W = (g==0)?Whz:Whr;
    v = W[((kb-3)*128+kk)*128 + j];
  } else v = 0.f;
  Bt[i] = f2bf(v);
}
// Bth[c][k] = Whh[k>>7][k&127][c], c<128, k<384
__global__ void k_packh(const float* __restrict__ Whh, ushort* __restrict__ Bt){
  int i = blockIdx.x*256 + threadIdx.x;
  if(i>=128*384) return;
  int c = i/384, k = i - c*384;
  Bt[i] = f2bf(Whh[((k>>7)*128 + (k&127))*128 + c]);
}

extern "C" void kernel_launch(void* const* d_in, const int* in_sizes, int n_in,
                              void* d_out, int out_size, void* d_ws, size_t ws_size,
                              hipStream_t stream) {
  const float* x   = (const float*)d_in[0];
  const int*   ei  = (const int*)d_in[1];
  const float* Wxz = (const float*)d_in[2];
  const float* Whz = (const float*)d_in[3];
  const float* Wxr = (const float*)d_in[4];
  const float* Whr = (const float*)d_in[5];
  const float* Wxh = (const float*)d_in[6];
  const float* Whh = (const float*)d_in[7];
  const float* bxz = (const float*)d_in[8];
  const float* bhz = (const float*)d_in[9];
  const float* bxr = (const float*)d_in[10];
  const float* bhr = (const float*)d_in[11];
  const float* bxh = (const float*)d_in[12];
  const float* bhh = (const float*)d_in[13];
  const float* Wd1 = (const float*)d_in[14];
  const float* bd1 = (const float*)d_in[15];
  const float* Wd2 = (const float*)d_in[16];
  const float* bd2 = (const float*)d_in[17];
  float* out = (float*)d_out;

  char* p = (char*)d_ws;
  auto alloc = [&](size_t bytes)->void*{ void* r = (void*)p; p += (bytes+255)&~(size_t)255; return r; };
  const size_t NFB  = (size_t)NN*FF*4;   // fp32 N x 128
  const size_t NFB2 = (size_t)NN*FF*2;   // bf16 N x 128
  float* Ha   = (float*)alloc(NFB);
  float* Hb   = (float*)alloc(NFB);
  float* OX   = (float*)alloc((size_t)NN*384*4);
  float* Zb   = (float*)alloc(NFB);      // Z / decoder temp
  ushort* xtb = (ushort*)alloc(NFB2);
  ushort* A1b = (ushort*)alloc(NFB2);
  ushort* A2b = (ushort*)alloc(NFB2);
  ushort* A3b = (ushort*)alloc(NFB2);
  ushort* A4b = (ushort*)alloc(NFB2);
  ushort* HRb = (ushort*)alloc(NFB2);
  ushort* Hab = (ushort*)alloc(NFB2);
  ushort* Hbb = (ushort*)alloc(NFB2);
  ushort* Btx = (ushort*)alloc((size_t)384*768*2);
  ushort* Bth = (ushort*)alloc((size_t)128*384*2);
  float* dinv = (float*)alloc((size_t)NN*4);
  int* deg  = (int*)alloc((size_t)NN*4);
  int* cnt  = (int*)alloc((size_t)NN*4);
  int* cur  = (int*)alloc((size_t)NN*4);
  int* offs = (int*)alloc((size_t)(NN+1)*4);
  int* part = (int*)alloc((size_t)256*4);
  int* srcs = (int*)alloc((size_t)EE*4);
  float* wsrt = (float*)alloc((size_t)EE*4);

  const int eb = (EE+255)/256;
  const int nb = NBS;           // 196
  const int fb = (NN*FF+255)/256;
  const int sg = (NN+3)/4;
  const int MT = (NN+127)/128;  // 391

  k_packx<<<(384*768+255)/256,256,0,stream>>>(Wxz,Wxr,Wxh,Whz,Whr,Btx);
  k_packh<<<(128*384+255)/256,256,0,stream>>>(Whh,Bth);
  k_zero_f<<<fb,256,0,stream>>>(Ha, NN*FF);
  k_zero_f<<<(NN*FF/2+255)/256,256,0,stream>>>((float*)Hab, NN*FF/2);  // bf16 zeros

  float* Hc = Ha; float* Hn = Hb;
  ushort* Hcb = Hab; ushort* Hnb = Hbb;
  for(int t=0;t<TT;++t){
    const float* xt = x + (size_t)t*NN*FF;
    const int* src = ei + (size_t)t*2*EE;
    const int* dst = src + EE;
    k_cast<<<(NN*FF/4+255)/256,256,0,stream>>>(xt, xtb, NN*FF/4);
    k_zero2i<<<nb,256,0,stream>>>(deg,cnt,NN);
    k_count<<<eb,256,0,stream>>>(src,dst,deg,cnt);
    k_scanA<<<nb,256,0,stream>>>(cnt,offs,part);
    k_scanB<<<1,256,0,stream>>>(part);
    k_scanC<<<nb,256,0,stream>>>(deg,offs,part,dinv,cur);
    k_scatter<<<eb,256,0,stream>>>(src,dst,dinv,offs,cur,srcs,wsrt);
    // Chebyshev propagations (all bf16): x-path and H-path fused
    k_spmm2<<<sg,256,0,stream>>>(offs,srcs,wsrt, xtb,Hcb, nullptr,nullptr, A1b,A3b);
    k_spmm2<<<sg,256,0,stream>>>(offs,srcs,wsrt, A1b,A3b, xtb,Hcb,         A2b,A4b);
    // fused K=768 MFMA GEMM -> OX[:,0:384]
    dim3 g1(MT, 3);
    k_mgemm<<<g1,256,0,stream>>>(xtb,A1b,A2b,Hcb,A3b,A4b, Btx, OX, 768, 384, 0, 0);
    k_combA<<<fb,256,0,stream>>>(OX,Hc,bxz,bhz,bxr,bhr,Zb,HRb);
    // HR-path propagation + K=384 MFMA GEMM (accumulates into OX[:,256:384])
    k_spmm1<<<sg,256,0,stream>>>(offs,srcs,wsrt, HRb, nullptr, A3b);
    k_spmm1<<<sg,256,0,stream>>>(offs,srcs,wsrt, A3b, HRb,     A4b);
    dim3 g3(MT, 1);
    k_mgemm<<<g3,256,0,stream>>>(HRb,A3b,A4b,nullptr,nullptr,nullptr, Bth, OX, 384, 384, 256, 1);
    k_combB<<<fb,256,0,stream>>>(OX,Zb,Hc,bxh,bhh,Hn,Hnb);
    float* tmp=Hc; Hc=Hn; Hn=tmp;
    ushort* tb=Hcb; Hcb=Hnb; Hnb=tb;
  }
  // decoder: x_pred = relu(H@Wd1+bd1)@Wd2+bd2  (fp32)
  dim3 gd((NN+63)/64, 2);
  k_gemm<<<gd,256,0,stream>>>(Hc, Wd1, Zb, 128, 128, 128, bd1, 1);
  k_gemm<<<gd,256,0,stream>>>(Zb, Wd2, out, 128, 128, 128, bd2, 0);
  k_copy<<<fb,256,0,stream>>>(Hc, out + (size_t)NN*FF, NN*FF);
}